// Round 6
// baseline (298.274 us; speedup 1.0000x reference)
//
#include <hip/hip_runtime.h>
#include <hip/hip_bf16.h>
#include <stdint.h>

// Problem constants (from reference: N=4264, B=256, NG=8, GS=533, SAMPLE_NUM=10)
#define NN 4264
#define BB 256
#define GSZ 533
#define NGRP 8
#define NSWEEP 10
#define NSTEP (NSWEEP * NGRP)
#define DMAX 48   // exact-table cap (Poisson(15): P(deg>48) ~ 1e-11 per node)
#define DFIX 24   // packed fast-path depth, zero-padded; tail read from exact table
#define NF4 1066  // NN/4 float4s per row (17056 B, 16B-aligned)
#define NIT 17    // ceil(NF4/64) float4-iterations per wave

struct Keys { unsigned k0[NSTEP]; unsigned k1[NSTEP]; };

// ---- threefry2x32, exactly as JAX (20 rounds, key injections every 4) ----
#define TF_ROUND(x0, x1, r) { x0 += x1; x1 = (x1 << (r)) | (x1 >> (32 - (r))); x1 ^= x0; }
#define TF_BODY(K0, K1, C0, C1, O0, O1) {                                   \
  unsigned ks0 = (K0), ks1 = (K1), ks2 = (K0) ^ (K1) ^ 0x1BD11BDAu;          \
  unsigned x0 = (C0) + ks0, x1 = (C1) + ks1;                                 \
  TF_ROUND(x0, x1, 13) TF_ROUND(x0, x1, 15) TF_ROUND(x0, x1, 26) TF_ROUND(x0, x1, 6)  \
  x0 += ks1; x1 += ks2 + 1u;                                                 \
  TF_ROUND(x0, x1, 17) TF_ROUND(x0, x1, 29) TF_ROUND(x0, x1, 16) TF_ROUND(x0, x1, 24) \
  x0 += ks2; x1 += ks0 + 2u;                                                 \
  TF_ROUND(x0, x1, 13) TF_ROUND(x0, x1, 15) TF_ROUND(x0, x1, 26) TF_ROUND(x0, x1, 6)  \
  x0 += ks0; x1 += ks1 + 3u;                                                 \
  TF_ROUND(x0, x1, 17) TF_ROUND(x0, x1, 29) TF_ROUND(x0, x1, 16) TF_ROUND(x0, x1, 24) \
  x0 += ks1; x1 += ks2 + 4u;                                                 \
  TF_ROUND(x0, x1, 13) TF_ROUND(x0, x1, 15) TF_ROUND(x0, x1, 26) TF_ROUND(x0, x1, 6)  \
  x0 += ks2; x1 += ks0 + 5u;                                                 \
  (O0) = x0; (O1) = x1; }

static void tf_host(unsigned k0, unsigned k1, unsigned c0, unsigned c1,
                    unsigned* o0, unsigned* o1) {
  unsigned a, b;
  TF_BODY(k0, k1, c0, c1, a, b);
  *o0 = a; *o1 = b;
}

__device__ __forceinline__ void tf_dev(unsigned k0, unsigned k1, unsigned c0, unsigned c1,
                                       unsigned& o0, unsigned& o1) {
  TF_BODY(k0, k1, c0, c1, o0, o1);
}

// ---- Build tables: wave-per-row, full-row register prefetch, no barriers ----
// Row p = g*GSZ + i -> node = groups[p].
// pack4[p*DFIX + k]  = (bf16_rne(val) << 16) | (col << 2)  (fast path, zero-padded;
//                      low half is the LDS *byte* offset of m[col])
// exact8[p*DMAX + k] = {col, f32 val}                      (fallback + tail, ascending col)
// marg[p] = 2^-9 * sum_{k<DFIX} |val| + 2e-5               (screen margin bound)
__global__ __launch_bounds__(256) void build_ell(const float* __restrict__ J,
                                                 const int* __restrict__ groups,
                                                 unsigned* __restrict__ pack4,
                                                 int2* __restrict__ exact8,
                                                 int* __restrict__ deg,
                                                 float* __restrict__ marg) {
  const int wv = threadIdx.x >> 6, lane = threadIdx.x & 63;
  const int p = blockIdx.x * 4 + wv;
  if (p >= NN) return;
  const int node = groups[p];
  const float4* row = (const float4*)(J + (size_t)node * NN);  // NF4 float4s, 16B-aligned

  // Phase 1: issue ALL row loads (17 KB/wave in flight -> HBM BW-bound, not latency)
  float4 vv[NIT];
#pragma unroll
  for (int it = 0; it < NIT; ++it) {
    const int q = it * 64 + lane;
    vv[it] = (q < NF4) ? row[q] : make_float4(0.0f, 0.0f, 0.0f, 0.0f);
  }

  // Phase 2: ballot compaction on registers (exact ascending-column order)
  int cnt = 0;
  float asum = 0.0f;
#pragma unroll
  for (int it = 0; it < NIT; ++it) {
    const float4 v = vv[it];
    const int c0 = (it * 64 + lane) * 4;
#define COMP(X, CIDX) {                                                        \
      const bool nz = ((X) != 0.0f);                                           \
      const unsigned long long mk = __ballot(nz);                              \
      const int rk = cnt + __popcll(mk & ((1ull << lane) - 1ull));             \
      if (nz) {                                                                \
        if (rk < DFIX) {                                                       \
          const unsigned bits = __float_as_uint(X);                            \
          const unsigned bf = (bits + 0x7fffu + ((bits >> 16) & 1u)) >> 16;    \
          pack4[(size_t)p * DFIX + rk] = (bf << 16) | ((unsigned)(CIDX) << 2); \
          asum += fabsf(X);                                                    \
        }                                                                      \
        if (rk < DMAX)                                                         \
          exact8[(size_t)p * DMAX + rk] = make_int2((CIDX), __float_as_int(X));\
      }                                                                        \
      cnt += __popcll(mk); }
    COMP(v.x, c0 + 0) COMP(v.y, c0 + 1) COMP(v.z, c0 + 2) COMP(v.w, c0 + 3)
#undef COMP
  }
  // zero-pad packed row
  for (int k = cnt + lane; k < DFIX; k += 64) pack4[(size_t)p * DFIX + k] = 0u;
  // wave-reduce abs-sum
  for (int s = 1; s < 64; s <<= 1) asum += __shfl_xor(asum, s, 64);
  if (lane == 0) {
    deg[p] = (cnt > DMAX) ? DMAX : cnt;
    marg[p] = asum * 0.001953125f + 2e-5f;  // 2^-9 * sum|v| + f32/tanhf slack
  }
}

// ---- Full Gibbs chain: one workgroup per batch row (rows are independent) ----
// 576 threads = 9 waves: one node per thread per group-step. The pack table
// for group g+1 is prefetched into registers while group g finishes
// (threefry/tanh/barriers), hiding the per-step L2 latency.
__global__ __launch_bounds__(576) void gibbs(const float* __restrict__ m0,
                                             const float* __restrict__ H,
                                             const int* __restrict__ groups,
                                             const unsigned* __restrict__ pack4,
                                             const int2* __restrict__ exact8,
                                             const int* __restrict__ deg,
                                             const float* __restrict__ marg,
                                             float* __restrict__ out,
                                             Keys keys) {
  __shared__ float m_lds[NN];
  const int b = blockIdx.x;
  const int i = threadIdx.x;
  const bool active = (i < GSZ);

  for (int n = i; n < NN; n += 576) m_lds[n] = m0[(size_t)b * NN + n];

  // Per-thread per-group preload (step-invariant).
  int nodeg[NGRP];
  float hg[NGRP], mgg[NGRP];
  int dgg[NGRP];
  if (active) {
#pragma unroll
    for (int g = 0; g < NGRP; ++g) {
      const int p = g * GSZ + i;
      nodeg[g] = groups[p];
      hg[g] = H[nodeg[g]];
      dgg[g] = deg[p];
      mgg[g] = marg[p];
    }
  }

  const unsigned c = (unsigned)(b * GSZ + i);

  // Prime the pack-word pipeline with group 0.
  uint4 w0, w1, w2, w3, w4, w5;
  if (active) {
    const uint4* q = (const uint4*)(pack4 + (size_t)(0 * GSZ + i) * DFIX);
    w0 = q[0]; w1 = q[1]; w2 = q[2]; w3 = q[3]; w4 = q[4]; w5 = q[5];
  }
  __syncthreads();

#pragma unroll 1
  for (int t = 0; t < NSWEEP; ++t) {
#pragma unroll
    for (int g = 0; g < NGRP; ++g) {
      const int step = t * NGRP + g;
      const unsigned k0 = keys.k0[step];
      const unsigned k1 = keys.k1[step];
      float nv = 0.0f;
      uint4 n0, n1, n2, n3, n4, n5;
      if (active) {
        // threefry first: pure ALU, independent of m_lds -> fills load shadow
        unsigned o0, o1;
        tf_dev(k0, k1, 0u, c, o0, o1);
        const unsigned bits = o0 ^ o1;
        const float u = __uint_as_float((bits >> 9) | 0x3f800000u) - 1.0f;
        const float r = u * 2.0f - 1.0f;  // exact in f32

        // gather-sum from current registers
        float a0 = 0.0f, a1 = 0.0f, a2 = 0.0f, a3 = 0.0f;
        // value = high-16 bits as f32 (bf16<<16); addr = low-16 = byte offset
#define MV(W)  (*(const float*)((const char*)m_lds + ((W) & 0xFFFCu)))
#define ACC(W) \
        a0 += __uint_as_float((W).x & 0xFFFF0000u) * MV((W).x); \
        a1 += __uint_as_float((W).y & 0xFFFF0000u) * MV((W).y); \
        a2 += __uint_as_float((W).z & 0xFFFF0000u) * MV((W).z); \
        a3 += __uint_as_float((W).w & 0xFFFF0000u) * MV((W).w);
        ACC(w0) ACC(w1) ACC(w2) ACC(w3) ACC(w4) ACC(w5)
#undef ACC
#undef MV

        // prefetch next group-step's pack words (table is constant -> no dep
        // on the barriers/scatter; wraps to group 0 for the next sweep)
        {
          const int gn = (g + 1) & (NGRP - 1);
          const uint4* qn = (const uint4*)(pack4 + (size_t)(gn * GSZ + i) * DFIX);
          n0 = qn[0]; n1 = qn[1]; n2 = qn[2]; n3 = qn[3]; n4 = qn[4]; n5 = qn[5];
        }

        const int dg = dgg[g];
        const int2* ep = exact8 + (size_t)(g * GSZ + i) * DMAX;
        if (__builtin_expect(dg > DFIX, 0)) {
          for (int k = DFIX; k < dg; ++k) {
            const int2 e = ep[k];
            a0 += __int_as_float(e.y) * m_lds[e.x];
          }
        }
        const float I = ((a0 + a1) + (a2 + a3)) + hg[g];

        const float th = tanhf(I);
        const float d = th - r;
        if (__builtin_expect(fabsf(d) > mgg[g], 1)) {
          // |tanhf(I_fast) - tanh64(I_exact)| <= marg  ->  sign matches exact
          nv = (d > 0.0f) ? 1.0f : -1.0f;
        } else {
          // boundary-close: settle in f64 from exact f32 table (ascending col)
          double I64 = (double)hg[g];
          for (int k = 0; k < dg; ++k) {
            const int2 e = ep[k];
            I64 += (double)__int_as_float(e.y) * (double)m_lds[e.x];
          }
          const double diff = tanh(I64) - (double)r;
          nv = (diff > 0.0) ? 1.0f : ((diff < 0.0) ? -1.0f : 0.0f);
        }
      }
      __syncthreads();                  // all gathers done
      if (active) m_lds[nodeg[g]] = nv; // compute-all-then-set semantics
      __syncthreads();                  // scatter visible before next group
      w0 = n0; w1 = n1; w2 = n2; w3 = n3; w4 = n4; w5 = n5;
    }
  }

  for (int n = i; n < NN; n += 576) out[(size_t)b * NN + n] = m_lds[n];
}

extern "C" void kernel_launch(void* const* d_in, const int* in_sizes, int n_in,
                              void* d_out, int out_size, void* d_ws, size_t ws_size,
                              hipStream_t stream) {
  const float* m0     = (const float*)d_in[0];
  const float* J      = (const float*)d_in[1];
  const float* H      = (const float*)d_in[2];
  const int*   groups = (const int*)d_in[3];
  // d_in[4] = sample_num (=10, hardcoded as NSWEEP)

  // Workspace: pack4[NN*DFIX] u32 (409 KB) | exact8[NN*DMAX] int2 (1.64 MB)
  //          | deg[NN] i32 | marg[NN] f32   -> total ~2.08 MB
  char* ws = (char*)d_ws;
  unsigned* pack4  = (unsigned*)ws;                     ws += (size_t)NN * DFIX * 4;
  int2*     exact8 = (int2*)ws;                         ws += (size_t)NN * DMAX * 8;
  int*      deg    = (int*)ws;                          ws += (size_t)NN * 4;
  float*    marg   = (float*)ws;

  // Host-side key schedule, jax_threefry_partitionable=True (fold-like split):
  // key(42) -> (0, 42); split(key, n)[i] = threefry2x32(key, (0, i)).
  Keys keys;
  for (int t = 0; t < NSWEEP; ++t) {
    unsigned ik0, ik1;
    tf_host(0u, 42u, 0u, (unsigned)t, &ik0, &ik1);
    for (int g = 0; g < NGRP; ++g) {
      unsigned gk0, gk1;
      tf_host(ik0, ik1, 0u, (unsigned)g, &gk0, &gk1);
      keys.k0[t * NGRP + g] = gk0;
      keys.k1[t * NGRP + g] = gk1;
    }
  }

  build_ell<<<(NN + 3) / 4, 256, 0, stream>>>(J, groups, pack4, exact8, deg, marg);
  gibbs<<<BB, 576, 0, stream>>>(m0, H, groups, pack4, exact8, deg, marg,
                                (float*)d_out, keys);
}

// Round 7
// 289.842 us; speedup vs baseline: 1.0291x; 1.0291x over previous
//
#include <hip/hip_runtime.h>
#include <hip/hip_bf16.h>
#include <stdint.h>

// Problem constants (from reference: N=4264, B=256, NG=8, GS=533, SAMPLE_NUM=10)
#define NN 4264
#define BB 256
#define GSZ 533
#define NGRP 8
#define NSWEEP 10
#define NSTEP (NSWEEP * NGRP)
#define NTOT (BB * GSZ)   // 136448 = 533 * 256 randoms per step
#define DMAX 48   // exact-table cap (Poisson(15): P(deg>48) ~ 1e-11 per node)
#define DFIX 24   // packed fast-path depth, zero-padded; tail read from exact table
#define NF4 1066  // NN/4 float4s per row (17056 B, 16B-aligned)
#define NIT 17    // ceil(NF4/64) float4-iterations per wave

struct Keys { unsigned k0[NSTEP]; unsigned k1[NSTEP]; };

// ---- threefry2x32, exactly as JAX (20 rounds, key injections every 4) ----
#define TF_ROUND(x0, x1, r) { x0 += x1; x1 = (x1 << (r)) | (x1 >> (32 - (r))); x1 ^= x0; }
#define TF_BODY(K0, K1, C0, C1, O0, O1) {                                   \
  unsigned ks0 = (K0), ks1 = (K1), ks2 = (K0) ^ (K1) ^ 0x1BD11BDAu;          \
  unsigned x0 = (C0) + ks0, x1 = (C1) + ks1;                                 \
  TF_ROUND(x0, x1, 13) TF_ROUND(x0, x1, 15) TF_ROUND(x0, x1, 26) TF_ROUND(x0, x1, 6)  \
  x0 += ks1; x1 += ks2 + 1u;                                                 \
  TF_ROUND(x0, x1, 17) TF_ROUND(x0, x1, 29) TF_ROUND(x0, x1, 16) TF_ROUND(x0, x1, 24) \
  x0 += ks2; x1 += ks0 + 2u;                                                 \
  TF_ROUND(x0, x1, 13) TF_ROUND(x0, x1, 15) TF_ROUND(x0, x1, 26) TF_ROUND(x0, x1, 6)  \
  x0 += ks0; x1 += ks1 + 3u;                                                 \
  TF_ROUND(x0, x1, 17) TF_ROUND(x0, x1, 29) TF_ROUND(x0, x1, 16) TF_ROUND(x0, x1, 24) \
  x0 += ks1; x1 += ks2 + 4u;                                                 \
  TF_ROUND(x0, x1, 13) TF_ROUND(x0, x1, 15) TF_ROUND(x0, x1, 26) TF_ROUND(x0, x1, 6)  \
  x0 += ks2; x1 += ks0 + 5u;                                                 \
  (O0) = x0; (O1) = x1; }

static void tf_host(unsigned k0, unsigned k1, unsigned c0, unsigned c1,
                    unsigned* o0, unsigned* o1) {
  unsigned a, b;
  TF_BODY(k0, k1, c0, c1, a, b);
  *o0 = a; *o1 = b;
}

__device__ __forceinline__ void tf_dev(unsigned k0, unsigned k1, unsigned c0, unsigned c1,
                                       unsigned& o0, unsigned& o1) {
  TF_BODY(k0, k1, c0, c1, o0, o1);
}

// ---- Precompute A[step][c] = atanhf(r(step, c)) for all 80 x 136448 draws ----
// sign(tanh(I) - r) == sign(I - atanh(r)) (tanh monotone); r = -1 -> A = -inf
// -> I - A = +inf -> +1, correct. Removes threefry+tanhf from the gibbs chain.
__global__ __launch_bounds__(256) void rng_atanh(float* __restrict__ A, Keys keys) {
  const int step = blockIdx.x / GSZ;          // block-uniform
  const int chunk = blockIdx.x % GSZ;
  const unsigned c = (unsigned)(chunk * 256 + threadIdx.x);  // < NTOT (533*256)
  unsigned o0, o1;
  tf_dev(keys.k0[step], keys.k1[step], 0u, c, o0, o1);
  const unsigned bits = o0 ^ o1;
  const float u = __uint_as_float((bits >> 9) | 0x3f800000u) - 1.0f;
  const float r = u * 2.0f - 1.0f;            // exact in f32
  const float a = 0.5f * logf((1.0f + r) / (1.0f - r));  // atanh(r); -inf at r=-1
  A[(size_t)step * NTOT + c] = a;
}

// ---- Build tables: wave-per-row, full-row register prefetch, no barriers ----
// Row p = g*GSZ + i -> node = groups[p].
// pack4[p*DFIX + k]  = (bf16_rne(val) << 16) | (col << 2)  (fast path, zero-padded;
//                      low half is the LDS *byte* offset of m[col])
// exact8[p*DMAX + k] = {col, f32 val}                      (fallback + tail, ascending col)
// marg[p] = 2^-9 * sum_{k<DFIX} |val| + 2e-5               (screen margin bound;
//           covers bf16 value error + f32 sum error + atanhf/tanhf error ~3e-6)
__global__ __launch_bounds__(256) void build_ell(const float* __restrict__ J,
                                                 const int* __restrict__ groups,
                                                 unsigned* __restrict__ pack4,
                                                 int2* __restrict__ exact8,
                                                 int* __restrict__ deg,
                                                 float* __restrict__ marg) {
  const int wv = threadIdx.x >> 6, lane = threadIdx.x & 63;
  const int p = blockIdx.x * 4 + wv;
  if (p >= NN) return;
  const int node = groups[p];
  const float4* row = (const float4*)(J + (size_t)node * NN);  // NF4 float4s, 16B-aligned

  // Phase 1: issue ALL row loads (17 KB/wave in flight -> HBM BW-bound, not latency)
  float4 vv[NIT];
#pragma unroll
  for (int it = 0; it < NIT; ++it) {
    const int q = it * 64 + lane;
    vv[it] = (q < NF4) ? row[q] : make_float4(0.0f, 0.0f, 0.0f, 0.0f);
  }

  // Phase 2: ballot compaction on registers (exact ascending-column order)
  int cnt = 0;
  float asum = 0.0f;
#pragma unroll
  for (int it = 0; it < NIT; ++it) {
    const float4 v = vv[it];
    const int c0 = (it * 64 + lane) * 4;
#define COMP(X, CIDX) {                                                        \
      const bool nz = ((X) != 0.0f);                                           \
      const unsigned long long mk = __ballot(nz);                              \
      const int rk = cnt + __popcll(mk & ((1ull << lane) - 1ull));             \
      if (nz) {                                                                \
        if (rk < DFIX) {                                                       \
          const unsigned bits = __float_as_uint(X);                            \
          const unsigned bf = (bits + 0x7fffu + ((bits >> 16) & 1u)) >> 16;    \
          pack4[(size_t)p * DFIX + rk] = (bf << 16) | ((unsigned)(CIDX) << 2); \
          asum += fabsf(X);                                                    \
        }                                                                      \
        if (rk < DMAX)                                                         \
          exact8[(size_t)p * DMAX + rk] = make_int2((CIDX), __float_as_int(X));\
      }                                                                        \
      cnt += __popcll(mk); }
    COMP(v.x, c0 + 0) COMP(v.y, c0 + 1) COMP(v.z, c0 + 2) COMP(v.w, c0 + 3)
#undef COMP
  }
  // zero-pad packed row
  for (int k = cnt + lane; k < DFIX; k += 64) pack4[(size_t)p * DFIX + k] = 0u;
  // wave-reduce abs-sum
  for (int s = 1; s < 64; s <<= 1) asum += __shfl_xor(asum, s, 64);
  if (lane == 0) {
    deg[p] = (cnt > DMAX) ? DMAX : cnt;
    marg[p] = asum * 0.001953125f + 2e-5f;  // 2^-9 * sum|v| + slack
  }
}

// ---- Full Gibbs chain: one workgroup per batch row (rows are independent) ----
// 576 threads = 9 waves: one node per thread per group-step.
// USE_A: decision = sign(I - A) with A precomputed; fallback recomputes
// threefry + f64 exactly. !USE_A: round-5 proven path (ws too small).
template <bool USE_A>
__global__ __launch_bounds__(576) void gibbs(const float* __restrict__ m0,
                                             const float* __restrict__ H,
                                             const int* __restrict__ groups,
                                             const unsigned* __restrict__ pack4,
                                             const int2* __restrict__ exact8,
                                             const int* __restrict__ deg,
                                             const float* __restrict__ marg,
                                             const float* __restrict__ Atab,
                                             float* __restrict__ out,
                                             Keys keys) {
  __shared__ float m_lds[NN];
  const int b = blockIdx.x;
  const int i = threadIdx.x;
  const bool active = (i < GSZ);

  for (int n = i; n < NN; n += 576) m_lds[n] = m0[(size_t)b * NN + n];

  // Per-thread per-group preload (step-invariant).
  int nodeg[NGRP];
  float hg[NGRP], mgg[NGRP];
  int dgg[NGRP];
  if (active) {
#pragma unroll
    for (int g = 0; g < NGRP; ++g) {
      const int p = g * GSZ + i;
      nodeg[g] = groups[p];
      hg[g] = H[nodeg[g]];
      dgg[g] = deg[p];
      mgg[g] = marg[p];
    }
  }
  __syncthreads();

  const unsigned c = (unsigned)(b * GSZ + i);

  float Acur = 0.0f;
  if (USE_A && active) Acur = Atab[(size_t)0 * NTOT + c];

#pragma unroll 1
  for (int t = 0; t < NSWEEP; ++t) {
#pragma unroll
    for (int g = 0; g < NGRP; ++g) {
      const int step = t * NGRP + g;
      float nv = 0.0f;
      float Anext = 0.0f;
      if (active) {
        // prefetch next step's threshold (4 B -> no spill risk); consumed
        // next iteration, ~full step of latency shadow
        if (USE_A) {
          const int sn = (step + 1 < NSTEP) ? step + 1 : step;
          Anext = Atab[(size_t)sn * NTOT + c];
        }

        const int p = g * GSZ + i;
        // 24 packed entries = 6 contiguous uint4 (96 B/thread, coalesced per wave)
        const uint4* q = (const uint4*)(pack4 + (size_t)p * DFIX);
        const uint4 w0 = q[0], w1 = q[1], w2 = q[2], w3 = q[3], w4 = q[4], w5 = q[5];
        float a0 = 0.0f, a1 = 0.0f, a2 = 0.0f, a3 = 0.0f;
        // value = high-16 bits as f32 (bf16<<16); addr = low-16 = byte offset
#define MV(W)  (*(const float*)((const char*)m_lds + ((W) & 0xFFFCu)))
#define ACC(W) \
        a0 += __uint_as_float((W).x & 0xFFFF0000u) * MV((W).x); \
        a1 += __uint_as_float((W).y & 0xFFFF0000u) * MV((W).y); \
        a2 += __uint_as_float((W).z & 0xFFFF0000u) * MV((W).z); \
        a3 += __uint_as_float((W).w & 0xFFFF0000u) * MV((W).w);
        ACC(w0) ACC(w1) ACC(w2) ACC(w3) ACC(w4) ACC(w5)
#undef ACC
#undef MV
        const int dg = dgg[g];
        const int2* ep = exact8 + (size_t)p * DMAX;
        if (__builtin_expect(dg > DFIX, 0)) {
          for (int k = DFIX; k < dg; ++k) {
            const int2 e = ep[k];
            a0 += __int_as_float(e.y) * m_lds[e.x];
          }
        }
        const float I = ((a0 + a1) + (a2 + a3)) + hg[g];

        bool fast;
        float d;
        float r = 0.0f;
        if (USE_A) {
          d = I - Acur;               // sign(I - atanh(r)) == sign(tanh(I) - r)
          fast = (fabsf(d) > mgg[g]);
        } else {
          unsigned o0, o1;
          tf_dev(keys.k0[step], keys.k1[step], 0u, c, o0, o1);
          const unsigned bits = o0 ^ o1;
          const float u = __uint_as_float((bits >> 9) | 0x3f800000u) - 1.0f;
          r = u * 2.0f - 1.0f;
          d = tanhf(I) - r;
          fast = (fabsf(d) > mgg[g]);
        }
        if (__builtin_expect(fast, 1)) {
          nv = (d > 0.0f) ? 1.0f : -1.0f;
        } else {
          // boundary-close: settle in f64 from exact f32 table (ascending col)
          if (USE_A) {
            unsigned o0, o1;
            tf_dev(keys.k0[step], keys.k1[step], 0u, c, o0, o1);
            const unsigned bits = o0 ^ o1;
            const float u = __uint_as_float((bits >> 9) | 0x3f800000u) - 1.0f;
            r = u * 2.0f - 1.0f;
          }
          double I64 = (double)hg[g];
          for (int k = 0; k < dg; ++k) {
            const int2 e = ep[k];
            I64 += (double)__int_as_float(e.y) * (double)m_lds[e.x];
          }
          const double diff = tanh(I64) - (double)r;
          nv = (diff > 0.0) ? 1.0f : ((diff < 0.0) ? -1.0f : 0.0f);
        }
      }
      __syncthreads();                  // all gathers done
      if (active) m_lds[nodeg[g]] = nv; // compute-all-then-set semantics
      __syncthreads();                  // scatter visible before next group
      Acur = Anext;
    }
  }

  for (int n = i; n < NN; n += 576) out[(size_t)b * NN + n] = m_lds[n];
}

extern "C" void kernel_launch(void* const* d_in, const int* in_sizes, int n_in,
                              void* d_out, int out_size, void* d_ws, size_t ws_size,
                              hipStream_t stream) {
  const float* m0     = (const float*)d_in[0];
  const float* J      = (const float*)d_in[1];
  const float* H      = (const float*)d_in[2];
  const int*   groups = (const int*)d_in[3];
  // d_in[4] = sample_num (=10, hardcoded as NSWEEP)

  // Workspace: pack4[NN*DFIX] u32 (409 KB) | exact8[NN*DMAX] int2 (1.64 MB)
  //          | deg[NN] i32 | marg[NN] f32 | A[NSTEP*NTOT] f32 (43.7 MB)
  char* ws = (char*)d_ws;
  unsigned* pack4  = (unsigned*)ws;                     ws += (size_t)NN * DFIX * 4;
  int2*     exact8 = (int2*)ws;                         ws += (size_t)NN * DMAX * 8;
  int*      deg    = (int*)ws;                          ws += (size_t)NN * 4;
  float*    marg   = (float*)ws;                        ws += (size_t)NN * 4;
  float*    Atab   = (float*)ws;                        ws += (size_t)NSTEP * NTOT * 4;
  const bool use_a = ((size_t)(ws - (char*)d_ws) <= ws_size);  // ws_size fixed -> graph-safe

  // Host-side key schedule, jax_threefry_partitionable=True (fold-like split):
  // key(42) -> (0, 42); split(key, n)[i] = threefry2x32(key, (0, i)).
  Keys keys;
  for (int t = 0; t < NSWEEP; ++t) {
    unsigned ik0, ik1;
    tf_host(0u, 42u, 0u, (unsigned)t, &ik0, &ik1);
    for (int g = 0; g < NGRP; ++g) {
      unsigned gk0, gk1;
      tf_host(ik0, ik1, 0u, (unsigned)g, &gk0, &gk1);
      keys.k0[t * NGRP + g] = gk0;
      keys.k1[t * NGRP + g] = gk1;
    }
  }

  build_ell<<<(NN + 3) / 4, 256, 0, stream>>>(J, groups, pack4, exact8, deg, marg);
  if (use_a) {
    rng_atanh<<<NSTEP * GSZ, 256, 0, stream>>>(Atab, keys);
    gibbs<true><<<BB, 576, 0, stream>>>(m0, H, groups, pack4, exact8, deg, marg,
                                        Atab, (float*)d_out, keys);
  } else {
    gibbs<false><<<BB, 576, 0, stream>>>(m0, H, groups, pack4, exact8, deg, marg,
                                         Atab, (float*)d_out, keys);
  }
}

// Round 8
// 284.595 us; speedup vs baseline: 1.0481x; 1.0184x over previous
//
#include <hip/hip_runtime.h>
#include <hip/hip_bf16.h>
#include <stdint.h>

// Problem constants (from reference: N=4264, B=256, NG=8, GS=533, SAMPLE_NUM=10)
#define NN 4264
#define BB 256
#define GSZ 533
#define NGRP 8
#define NSWEEP 10
#define NSTEP (NSWEEP * NGRP)
#define NTOT (BB * GSZ)   // 136448 randoms per step
#define DMAX 48   // exact-table cap (Poisson(15): P(deg>48) ~ 1e-11 per node)
#define DFIX 24   // packed fast-path depth, zero-padded; tail read from exact table
#define NF4 1066  // NN/4 float4s per row (17056 B, 16B-aligned)
#define NIT 17    // ceil(NF4/64) float4-iterations per wave
#define NBBUILD ((NN + 3) / 4)   // 1066 build blocks in the merged prep kernel

struct Keys { unsigned k0[NSTEP]; unsigned k1[NSTEP]; };

// ---- threefry2x32, exactly as JAX (20 rounds, key injections every 4) ----
#define TF_ROUND(x0, x1, r) { x0 += x1; x1 = (x1 << (r)) | (x1 >> (32 - (r))); x1 ^= x0; }
#define TF_BODY(K0, K1, C0, C1, O0, O1) {                                   \
  unsigned ks0 = (K0), ks1 = (K1), ks2 = (K0) ^ (K1) ^ 0x1BD11BDAu;          \
  unsigned x0 = (C0) + ks0, x1 = (C1) + ks1;                                 \
  TF_ROUND(x0, x1, 13) TF_ROUND(x0, x1, 15) TF_ROUND(x0, x1, 26) TF_ROUND(x0, x1, 6)  \
  x0 += ks1; x1 += ks2 + 1u;                                                 \
  TF_ROUND(x0, x1, 17) TF_ROUND(x0, x1, 29) TF_ROUND(x0, x1, 16) TF_ROUND(x0, x1, 24) \
  x0 += ks2; x1 += ks0 + 2u;                                                 \
  TF_ROUND(x0, x1, 13) TF_ROUND(x0, x1, 15) TF_ROUND(x0, x1, 26) TF_ROUND(x0, x1, 6)  \
  x0 += ks0; x1 += ks1 + 3u;                                                 \
  TF_ROUND(x0, x1, 17) TF_ROUND(x0, x1, 29) TF_ROUND(x0, x1, 16) TF_ROUND(x0, x1, 24) \
  x0 += ks1; x1 += ks2 + 4u;                                                 \
  TF_ROUND(x0, x1, 13) TF_ROUND(x0, x1, 15) TF_ROUND(x0, x1, 26) TF_ROUND(x0, x1, 6)  \
  x0 += ks2; x1 += ks0 + 5u;                                                 \
  (O0) = x0; (O1) = x1; }

static void tf_host(unsigned k0, unsigned k1, unsigned c0, unsigned c1,
                    unsigned* o0, unsigned* o1) {
  unsigned a, b;
  TF_BODY(k0, k1, c0, c1, a, b);
  *o0 = a; *o1 = b;
}

__device__ __forceinline__ void tf_dev(unsigned k0, unsigned k1, unsigned c0, unsigned c1,
                                       unsigned& o0, unsigned& o1) {
  TF_BODY(k0, k1, c0, c1, o0, o1);
}

// ---- Merged prep: blocks [0, NBBUILD) build tables; the rest fill Atab ----
// Build (wave-per-row, full-row register prefetch):
//   pack4[p*DFIX + k]  = (bf16_rne(val) << 16) | (col << 2)   (zero-padded)
//   exact8[p*DMAX + k] = {col, f32 val}                       (ascending col)
//   marg[p] = 2^-9 * sum_{k<DFIX} |val| + 2e-5
// RNG: A[step][c] = atanhf(r(step, c)); sign(tanh(I)-r) == sign(I - atanh(r)).
__global__ __launch_bounds__(256) void prep(const float* __restrict__ J,
                                            const int* __restrict__ groups,
                                            unsigned* __restrict__ pack4,
                                            int2* __restrict__ exact8,
                                            int* __restrict__ deg,
                                            float* __restrict__ marg,
                                            float* __restrict__ Atab,
                                            Keys keys) {
  if (blockIdx.x >= NBBUILD) {
    // ---- RNG part: one thread per (step, c) draw ----
    const int idx = blockIdx.x - NBBUILD;
    const int step = idx / GSZ;
    const int chunk = idx % GSZ;
    const unsigned c = (unsigned)(chunk * 256 + threadIdx.x);  // < NTOT
    unsigned o0, o1;
    tf_dev(keys.k0[step], keys.k1[step], 0u, c, o0, o1);
    const unsigned bits = o0 ^ o1;
    const float u = __uint_as_float((bits >> 9) | 0x3f800000u) - 1.0f;
    const float r = u * 2.0f - 1.0f;            // exact in f32
    const float a = 0.5f * logf((1.0f + r) / (1.0f - r));  // atanh; -inf at r=-1
    Atab[(size_t)step * NTOT + c] = a;
    return;
  }
  // ---- Build part: wave-per-row ----
  const int wv = threadIdx.x >> 6, lane = threadIdx.x & 63;
  const int p = blockIdx.x * 4 + wv;
  if (p >= NN) return;
  const int node = groups[p];
  const float4* row = (const float4*)(J + (size_t)node * NN);

  // Phase 1: issue ALL row loads (17 KB/wave in flight -> BW-bound, not latency)
  float4 vv[NIT];
#pragma unroll
  for (int it = 0; it < NIT; ++it) {
    const int q = it * 64 + lane;
    vv[it] = (q < NF4) ? row[q] : make_float4(0.0f, 0.0f, 0.0f, 0.0f);
  }

  // Phase 2: ballot compaction on registers (exact ascending-column order)
  int cnt = 0;
  float asum = 0.0f;
#pragma unroll
  for (int it = 0; it < NIT; ++it) {
    const float4 v = vv[it];
    const int c0 = (it * 64 + lane) * 4;
#define COMP(X, CIDX) {                                                        \
      const bool nz = ((X) != 0.0f);                                           \
      const unsigned long long mk = __ballot(nz);                              \
      const int rk = cnt + __popcll(mk & ((1ull << lane) - 1ull));             \
      if (nz) {                                                                \
        if (rk < DFIX) {                                                       \
          const unsigned bits = __float_as_uint(X);                            \
          const unsigned bf = (bits + 0x7fffu + ((bits >> 16) & 1u)) >> 16;    \
          pack4[(size_t)p * DFIX + rk] = (bf << 16) | ((unsigned)(CIDX) << 2); \
          asum += fabsf(X);                                                    \
        }                                                                      \
        if (rk < DMAX)                                                         \
          exact8[(size_t)p * DMAX + rk] = make_int2((CIDX), __float_as_int(X));\
      }                                                                        \
      cnt += __popcll(mk); }
    COMP(v.x, c0 + 0) COMP(v.y, c0 + 1) COMP(v.z, c0 + 2) COMP(v.w, c0 + 3)
#undef COMP
  }
  for (int k = cnt + lane; k < DFIX; k += 64) pack4[(size_t)p * DFIX + k] = 0u;
  for (int s = 1; s < 64; s <<= 1) asum += __shfl_xor(asum, s, 64);
  if (lane == 0) {
    deg[p] = (cnt > DMAX) ? DMAX : cnt;
    marg[p] = asum * 0.001953125f + 2e-5f;  // 2^-9 * sum|v| + slack
  }
}

// ---- Full Gibbs chain: one workgroup per batch row (rows are independent) ----
// 576 threads = 9 waves, one node per thread per group-step.
// launch_bounds(576, 3): a 9-wave block needs 3 waves/EU -> VGPR budget ~170,
// so the next-step pack prefetch (24 VGPRs live across the barriers) does NOT
// spill (round-6 regression was spill-induced: WRITE_SIZE 7->28 MB at VGPR cap 84).
template <bool USE_A>
__global__ __launch_bounds__(576, 3) void gibbs(const float* __restrict__ m0,
                                                const float* __restrict__ H,
                                                const int* __restrict__ groups,
                                                const unsigned* __restrict__ pack4,
                                                const int2* __restrict__ exact8,
                                                const int* __restrict__ deg,
                                                const float* __restrict__ marg,
                                                const float* __restrict__ Atab,
                                                float* __restrict__ out,
                                                Keys keys) {
  __shared__ float m_lds[NN];
  const int b = blockIdx.x;
  const int i = threadIdx.x;
  const bool active = (i < GSZ);

  for (int n = i; n < NN; n += 576) m_lds[n] = m0[(size_t)b * NN + n];

  // Per-thread per-group preload (step-invariant).
  int nodeg[NGRP];
  float hg[NGRP], mgg[NGRP];
  int dgg[NGRP];
  if (active) {
#pragma unroll
    for (int g = 0; g < NGRP; ++g) {
      const int p = g * GSZ + i;
      nodeg[g] = groups[p];
      hg[g] = H[nodeg[g]];
      dgg[g] = deg[p];
      mgg[g] = marg[p];
    }
  }

  const unsigned c = (unsigned)(b * GSZ + i);

  // Prime the pipelines: group-0 pack words + step-0 threshold.
  uint4 w0, w1, w2, w3, w4, w5;
  float Acur = 0.0f;
  if (active) {
    const uint4* q = (const uint4*)(pack4 + (size_t)i * DFIX);
    w0 = q[0]; w1 = q[1]; w2 = q[2]; w3 = q[3]; w4 = q[4]; w5 = q[5];
    if (USE_A) Acur = Atab[c];
  }
  __syncthreads();

#pragma unroll 1
  for (int t = 0; t < NSWEEP; ++t) {
#pragma unroll
    for (int g = 0; g < NGRP; ++g) {
      const int step = t * NGRP + g;
      float nv = 0.0f;
      float Anext = 0.0f;
      uint4 n0, n1, n2, n3, n4, n5;
      if (active) {
        // Prefetch next group-step's pack words + threshold (table constant ->
        // independent of barriers/scatter; ~full step of latency shadow).
        {
          const int gn = (g + 1) & (NGRP - 1);
          const uint4* qn = (const uint4*)(pack4 + (size_t)(gn * GSZ + i) * DFIX);
          n0 = qn[0]; n1 = qn[1]; n2 = qn[2]; n3 = qn[3]; n4 = qn[4]; n5 = qn[5];
          if (USE_A) {
            const int sn = (step + 1 < NSTEP) ? step + 1 : step;
            Anext = Atab[(size_t)sn * NTOT + c];
          }
        }

        // Gather-sum from current registers.
        float a0 = 0.0f, a1 = 0.0f, a2 = 0.0f, a3 = 0.0f;
        // value = high-16 bits as f32 (bf16<<16); addr = low-16 = byte offset
#define MV(W)  (*(const float*)((const char*)m_lds + ((W) & 0xFFFCu)))
#define ACC(W) \
        a0 += __uint_as_float((W).x & 0xFFFF0000u) * MV((W).x); \
        a1 += __uint_as_float((W).y & 0xFFFF0000u) * MV((W).y); \
        a2 += __uint_as_float((W).z & 0xFFFF0000u) * MV((W).z); \
        a3 += __uint_as_float((W).w & 0xFFFF0000u) * MV((W).w);
        ACC(w0) ACC(w1) ACC(w2) ACC(w3) ACC(w4) ACC(w5)
#undef ACC
#undef MV
        const int dg = dgg[g];
        const int2* ep = exact8 + (size_t)(g * GSZ + i) * DMAX;
        if (__builtin_expect(dg > DFIX, 0)) {
          for (int k = DFIX; k < dg; ++k) {
            const int2 e = ep[k];
            a0 += __int_as_float(e.y) * m_lds[e.x];
          }
        }
        const float I = ((a0 + a1) + (a2 + a3)) + hg[g];

        bool fast;
        float d;
        float r = 0.0f;
        if (USE_A) {
          d = I - Acur;               // sign(I - atanh(r)) == sign(tanh(I) - r)
          fast = (fabsf(d) > mgg[g]);
        } else {
          unsigned o0, o1;
          tf_dev(keys.k0[step], keys.k1[step], 0u, c, o0, o1);
          const unsigned bits = o0 ^ o1;
          const float u = __uint_as_float((bits >> 9) | 0x3f800000u) - 1.0f;
          r = u * 2.0f - 1.0f;
          d = tanhf(I) - r;
          fast = (fabsf(d) > mgg[g]);
        }
        if (__builtin_expect(fast, 1)) {
          nv = (d > 0.0f) ? 1.0f : -1.0f;
        } else {
          // Boundary-close: settle in f64 from exact f32 table (ascending col).
          if (USE_A) {
            unsigned o0, o1;
            tf_dev(keys.k0[step], keys.k1[step], 0u, c, o0, o1);
            const unsigned bits = o0 ^ o1;
            const float u = __uint_as_float((bits >> 9) | 0x3f800000u) - 1.0f;
            r = u * 2.0f - 1.0f;
          }
          double I64 = (double)hg[g];
          for (int k = 0; k < dg; ++k) {
            const int2 e = ep[k];
            I64 += (double)__int_as_float(e.y) * (double)m_lds[e.x];
          }
          const double diff = tanh(I64) - (double)r;
          nv = (diff > 0.0) ? 1.0f : ((diff < 0.0) ? -1.0f : 0.0f);
        }
      }
      __syncthreads();                  // all gathers done
      if (active) m_lds[nodeg[g]] = nv; // compute-all-then-set semantics
      __syncthreads();                  // scatter visible before next group
      w0 = n0; w1 = n1; w2 = n2; w3 = n3; w4 = n4; w5 = n5;
      Acur = Anext;
    }
  }

  for (int n = i; n < NN; n += 576) out[(size_t)b * NN + n] = m_lds[n];
}

extern "C" void kernel_launch(void* const* d_in, const int* in_sizes, int n_in,
                              void* d_out, int out_size, void* d_ws, size_t ws_size,
                              hipStream_t stream) {
  const float* m0     = (const float*)d_in[0];
  const float* J      = (const float*)d_in[1];
  const float* H      = (const float*)d_in[2];
  const int*   groups = (const int*)d_in[3];
  // d_in[4] = sample_num (=10, hardcoded as NSWEEP)

  // Workspace: pack4[NN*DFIX] u32 (409 KB) | exact8[NN*DMAX] int2 (1.64 MB)
  //          | deg[NN] i32 | marg[NN] f32 | A[NSTEP*NTOT] f32 (43.7 MB)
  char* ws = (char*)d_ws;
  unsigned* pack4  = (unsigned*)ws;                     ws += (size_t)NN * DFIX * 4;
  int2*     exact8 = (int2*)ws;                         ws += (size_t)NN * DMAX * 8;
  int*      deg    = (int*)ws;                          ws += (size_t)NN * 4;
  float*    marg   = (float*)ws;                        ws += (size_t)NN * 4;
  float*    Atab   = (float*)ws;                        ws += (size_t)NSTEP * NTOT * 4;
  const bool use_a = ((size_t)(ws - (char*)d_ws) <= ws_size);  // fixed -> graph-safe

  // Host-side key schedule, jax_threefry_partitionable=True (fold-like split):
  // key(42) -> (0, 42); split(key, n)[i] = threefry2x32(key, (0, i)).
  Keys keys;
  for (int t = 0; t < NSWEEP; ++t) {
    unsigned ik0, ik1;
    tf_host(0u, 42u, 0u, (unsigned)t, &ik0, &ik1);
    for (int g = 0; g < NGRP; ++g) {
      unsigned gk0, gk1;
      tf_host(ik0, ik1, 0u, (unsigned)g, &gk0, &gk1);
      keys.k0[t * NGRP + g] = gk0;
      keys.k1[t * NGRP + g] = gk1;
    }
  }

  if (use_a) {
    prep<<<NBBUILD + NSTEP * GSZ, 256, 0, stream>>>(J, groups, pack4, exact8,
                                                    deg, marg, Atab, keys);
    gibbs<true><<<BB, 576, 0, stream>>>(m0, H, groups, pack4, exact8, deg, marg,
                                        Atab, (float*)d_out, keys);
  } else {
    prep<<<NBBUILD, 256, 0, stream>>>(J, groups, pack4, exact8,
                                      deg, marg, Atab, keys);
    gibbs<false><<<BB, 576, 0, stream>>>(m0, H, groups, pack4, exact8, deg, marg,
                                         Atab, (float*)d_out, keys);
  }
}

// Round 9
// 277.961 us; speedup vs baseline: 1.0731x; 1.0239x over previous
//
#include <hip/hip_runtime.h>
#include <hip/hip_bf16.h>
#include <stdint.h>

// Problem constants (from reference: N=4264, B=256, NG=8, GS=533, SAMPLE_NUM=10)
#define NN 4264
#define BB 256
#define GSZ 533
#define NGRP 8
#define NSWEEP 10
#define NSTEP (NSWEEP * NGRP)
#define DMAX 48   // exact-table cap (Poisson(15): P(deg>48) ~ 1e-11 per node)
#define DFIX 24   // packed fast-path depth, zero-padded; tail read from exact table
#define NF4 1066  // NN/4 float4s per row (17056 B, 16B-aligned)
#define NIT 17    // ceil(NF4/64) float4-iterations per wave

struct Keys { unsigned k0[NSTEP]; unsigned k1[NSTEP]; };

// ---- threefry2x32, exactly as JAX (20 rounds, key injections every 4) ----
#define TF_ROUND(x0, x1, r) { x0 += x1; x1 = (x1 << (r)) | (x1 >> (32 - (r))); x1 ^= x0; }
#define TF_BODY(K0, K1, C0, C1, O0, O1) {                                   \
  unsigned ks0 = (K0), ks1 = (K1), ks2 = (K0) ^ (K1) ^ 0x1BD11BDAu;          \
  unsigned x0 = (C0) + ks0, x1 = (C1) + ks1;                                 \
  TF_ROUND(x0, x1, 13) TF_ROUND(x0, x1, 15) TF_ROUND(x0, x1, 26) TF_ROUND(x0, x1, 6)  \
  x0 += ks1; x1 += ks2 + 1u;                                                 \
  TF_ROUND(x0, x1, 17) TF_ROUND(x0, x1, 29) TF_ROUND(x0, x1, 16) TF_ROUND(x0, x1, 24) \
  x0 += ks2; x1 += ks0 + 2u;                                                 \
  TF_ROUND(x0, x1, 13) TF_ROUND(x0, x1, 15) TF_ROUND(x0, x1, 26) TF_ROUND(x0, x1, 6)  \
  x0 += ks0; x1 += ks1 + 3u;                                                 \
  TF_ROUND(x0, x1, 17) TF_ROUND(x0, x1, 29) TF_ROUND(x0, x1, 16) TF_ROUND(x0, x1, 24) \
  x0 += ks1; x1 += ks2 + 4u;                                                 \
  TF_ROUND(x0, x1, 13) TF_ROUND(x0, x1, 15) TF_ROUND(x0, x1, 26) TF_ROUND(x0, x1, 6)  \
  x0 += ks2; x1 += ks0 + 5u;                                                 \
  (O0) = x0; (O1) = x1; }

static void tf_host(unsigned k0, unsigned k1, unsigned c0, unsigned c1,
                    unsigned* o0, unsigned* o1) {
  unsigned a, b;
  TF_BODY(k0, k1, c0, c1, a, b);
  *o0 = a; *o1 = b;
}

__device__ __forceinline__ void tf_dev(unsigned k0, unsigned k1, unsigned c0, unsigned c1,
                                       unsigned& o0, unsigned& o1) {
  TF_BODY(k0, k1, c0, c1, o0, o1);
}

// ---- Build tables: wave-per-row, full-row register prefetch, no barriers ----
// Row p = g*GSZ + i -> node = groups[p].
// pack4[p*DFIX + k]  = (bf16_rne(val) << 16) | (col << 2)   (zero-padded;
//                      low half is the LDS *byte* offset of m[col])
// exact8[p*DMAX + k] = {col, f32 val}                       (ascending col)
// marg[p] = 2^-9 * sum_{k<DFIX} |val| + 2e-5                (screen margin bound)
__global__ __launch_bounds__(256) void build_ell(const float* __restrict__ J,
                                                 const int* __restrict__ groups,
                                                 unsigned* __restrict__ pack4,
                                                 int2* __restrict__ exact8,
                                                 int* __restrict__ deg,
                                                 float* __restrict__ marg) {
  const int wv = threadIdx.x >> 6, lane = threadIdx.x & 63;
  const int p = blockIdx.x * 4 + wv;
  if (p >= NN) return;
  const int node = groups[p];
  const float4* row = (const float4*)(J + (size_t)node * NN);

  // Phase 1: issue ALL row loads (17 KB/wave in flight -> BW-bound, not latency)
  float4 vv[NIT];
#pragma unroll
  for (int it = 0; it < NIT; ++it) {
    const int q = it * 64 + lane;
    vv[it] = (q < NF4) ? row[q] : make_float4(0.0f, 0.0f, 0.0f, 0.0f);
  }

  // Phase 2: ballot compaction on registers (exact ascending-column order)
  int cnt = 0;
  float asum = 0.0f;
#pragma unroll
  for (int it = 0; it < NIT; ++it) {
    const float4 v = vv[it];
    const int c0 = (it * 64 + lane) * 4;
#define COMP(X, CIDX) {                                                        \
      const bool nz = ((X) != 0.0f);                                           \
      const unsigned long long mk = __ballot(nz);                              \
      const int rk = cnt + __popcll(mk & ((1ull << lane) - 1ull));             \
      if (nz) {                                                                \
        if (rk < DFIX) {                                                       \
          const unsigned bits = __float_as_uint(X);                            \
          const unsigned bf = (bits + 0x7fffu + ((bits >> 16) & 1u)) >> 16;    \
          pack4[(size_t)p * DFIX + rk] = (bf << 16) | ((unsigned)(CIDX) << 2); \
          asum += fabsf(X);                                                    \
        }                                                                      \
        if (rk < DMAX)                                                         \
          exact8[(size_t)p * DMAX + rk] = make_int2((CIDX), __float_as_int(X));\
      }                                                                        \
      cnt += __popcll(mk); }
    COMP(v.x, c0 + 0) COMP(v.y, c0 + 1) COMP(v.z, c0 + 2) COMP(v.w, c0 + 3)
#undef COMP
  }
  for (int k = cnt + lane; k < DFIX; k += 64) pack4[(size_t)p * DFIX + k] = 0u;
  for (int s = 1; s < 64; s <<= 1) asum += __shfl_xor(asum, s, 64);
  if (lane == 0) {
    deg[p] = (cnt > DMAX) ? DMAX : cnt;
    marg[p] = asum * 0.001953125f + 2e-5f;  // 2^-9 * sum|v| + slack
  }
}

// ---- Full Gibbs chain: one workgroup per batch row (rows are independent) ----
// 576 threads = 9 waves, one node per thread per group-step.
// Pack words for group g+1 prefetched at step top (table constant -> no
// barrier dependency); threefry (~105 VALU ops) recomputed in-loop — VALU is
// only ~20% busy and overlaps the LDS-pipe-bound gather, unlike the r8 Atab
// load which chained HBM latency into the pre-barrier vmcnt(0) drain.
__global__ __launch_bounds__(576, 3) void gibbs(const float* __restrict__ m0,
                                                const float* __restrict__ H,
                                                const int* __restrict__ groups,
                                                const unsigned* __restrict__ pack4,
                                                const int2* __restrict__ exact8,
                                                const int* __restrict__ deg,
                                                const float* __restrict__ marg,
                                                float* __restrict__ out,
                                                Keys keys) {
  __shared__ float m_lds[NN];
  const int b = blockIdx.x;
  const int i = threadIdx.x;
  const bool active = (i < GSZ);

  for (int n = i; n < NN; n += 576) m_lds[n] = m0[(size_t)b * NN + n];

  // Per-thread per-group preload (step-invariant).
  int nodeg[NGRP];
  float hg[NGRP], mgg[NGRP];
  int dgg[NGRP];
  if (active) {
#pragma unroll
    for (int g = 0; g < NGRP; ++g) {
      const int p = g * GSZ + i;
      nodeg[g] = groups[p];
      hg[g] = H[nodeg[g]];
      dgg[g] = deg[p];
      mgg[g] = marg[p];
    }
  }

  const unsigned c = (unsigned)(b * GSZ + i);

  // Prime the pack-word pipeline with group 0.
  uint4 w0, w1, w2, w3, w4, w5;
  if (active) {
    const uint4* q = (const uint4*)(pack4 + (size_t)i * DFIX);
    w0 = q[0]; w1 = q[1]; w2 = q[2]; w3 = q[3]; w4 = q[4]; w5 = q[5];
  }
  __syncthreads();

#pragma unroll 1
  for (int t = 0; t < NSWEEP; ++t) {
#pragma unroll
    for (int g = 0; g < NGRP; ++g) {
      const int step = t * NGRP + g;
      const unsigned k0 = keys.k0[step];
      const unsigned k1 = keys.k1[step];
      float nv = 0.0f;
      uint4 n0, n1, n2, n3, n4, n5;
      if (active) {
        // Prefetch next group-step's pack words (independent of barriers).
        {
          const int gn = (g + 1) & (NGRP - 1);
          const uint4* qn = (const uint4*)(pack4 + (size_t)(gn * GSZ + i) * DFIX);
          n0 = qn[0]; n1 = qn[1]; n2 = qn[2]; n3 = qn[3]; n4 = qn[4]; n5 = qn[5];
        }

        // threefry in the prefetch/gather shadow: pure VALU, no memory deps.
        unsigned o0, o1;
        tf_dev(k0, k1, 0u, c, o0, o1);
        const unsigned bits = o0 ^ o1;
        const float u = __uint_as_float((bits >> 9) | 0x3f800000u) - 1.0f;
        const float r = u * 2.0f - 1.0f;  // exact in f32

        // Gather-sum from current registers.
        float a0 = 0.0f, a1 = 0.0f, a2 = 0.0f, a3 = 0.0f;
        // value = high-16 bits as f32 (bf16<<16); addr = low-16 = byte offset
#define MV(W)  (*(const float*)((const char*)m_lds + ((W) & 0xFFFCu)))
#define ACC(W) \
        a0 += __uint_as_float((W).x & 0xFFFF0000u) * MV((W).x); \
        a1 += __uint_as_float((W).y & 0xFFFF0000u) * MV((W).y); \
        a2 += __uint_as_float((W).z & 0xFFFF0000u) * MV((W).z); \
        a3 += __uint_as_float((W).w & 0xFFFF0000u) * MV((W).w);
        ACC(w0) ACC(w1) ACC(w2) ACC(w3) ACC(w4) ACC(w5)
#undef ACC
#undef MV
        const int dg = dgg[g];
        const int2* ep = exact8 + (size_t)(g * GSZ + i) * DMAX;
        if (__builtin_expect(dg > DFIX, 0)) {
          for (int k = DFIX; k < dg; ++k) {
            const int2 e = ep[k];
            a0 += __int_as_float(e.y) * m_lds[e.x];
          }
        }
        const float I = ((a0 + a1) + (a2 + a3)) + hg[g];

        const float th = tanhf(I);
        const float d = th - r;
        if (__builtin_expect(fabsf(d) > mgg[g], 1)) {
          // |tanhf(I_fast) - tanh64(I_exact)| <= marg -> sign matches exact
          nv = (d > 0.0f) ? 1.0f : -1.0f;
        } else {
          // Boundary-close: settle in f64 from exact f32 table (ascending col).
          double I64 = (double)hg[g];
          for (int k = 0; k < dg; ++k) {
            const int2 e = ep[k];
            I64 += (double)__int_as_float(e.y) * (double)m_lds[e.x];
          }
          const double diff = tanh(I64) - (double)r;
          nv = (diff > 0.0) ? 1.0f : ((diff < 0.0) ? -1.0f : 0.0f);
        }
      }
      __syncthreads();                  // all gathers done
      if (active) m_lds[nodeg[g]] = nv; // compute-all-then-set semantics
      __syncthreads();                  // scatter visible before next group
      w0 = n0; w1 = n1; w2 = n2; w3 = n3; w4 = n4; w5 = n5;
    }
  }

  for (int n = i; n < NN; n += 576) out[(size_t)b * NN + n] = m_lds[n];
}

extern "C" void kernel_launch(void* const* d_in, const int* in_sizes, int n_in,
                              void* d_out, int out_size, void* d_ws, size_t ws_size,
                              hipStream_t stream) {
  const float* m0     = (const float*)d_in[0];
  const float* J      = (const float*)d_in[1];
  const float* H      = (const float*)d_in[2];
  const int*   groups = (const int*)d_in[3];
  // d_in[4] = sample_num (=10, hardcoded as NSWEEP)

  // Workspace: pack4[NN*DFIX] u32 (409 KB) | exact8[NN*DMAX] int2 (1.64 MB)
  //          | deg[NN] i32 | marg[NN] f32   -> ~2.08 MB total
  char* ws = (char*)d_ws;
  unsigned* pack4  = (unsigned*)ws;                     ws += (size_t)NN * DFIX * 4;
  int2*     exact8 = (int2*)ws;                         ws += (size_t)NN * DMAX * 8;
  int*      deg    = (int*)ws;                          ws += (size_t)NN * 4;
  float*    marg   = (float*)ws;

  // Host-side key schedule, jax_threefry_partitionable=True (fold-like split):
  // key(42) -> (0, 42); split(key, n)[i] = threefry2x32(key, (0, i)).
  Keys keys;
  for (int t = 0; t < NSWEEP; ++t) {
    unsigned ik0, ik1;
    tf_host(0u, 42u, 0u, (unsigned)t, &ik0, &ik1);
    for (int g = 0; g < NGRP; ++g) {
      unsigned gk0, gk1;
      tf_host(ik0, ik1, 0u, (unsigned)g, &gk0, &gk1);
      keys.k0[t * NGRP + g] = gk0;
      keys.k1[t * NGRP + g] = gk1;
    }
  }

  build_ell<<<(NN + 3) / 4, 256, 0, stream>>>(J, groups, pack4, exact8, deg, marg);
  gibbs<<<BB, 576, 0, stream>>>(m0, H, groups, pack4, exact8, deg, marg,
                                (float*)d_out, keys);
}

// Round 10
// 274.599 us; speedup vs baseline: 1.0862x; 1.0122x over previous
//
#include <hip/hip_runtime.h>
#include <hip/hip_bf16.h>
#include <stdint.h>

// Problem constants (from reference: N=4264, B=256, NG=8, GS=533, SAMPLE_NUM=10)
#define NN 4264
#define BB 256
#define GSZ 533
#define NGRP 8
#define NSWEEP 10
#define NSTEP (NSWEEP * NGRP)
#define DMAX 48   // exact-table cap (Poisson(15): P(deg>48) ~ 1e-11 per node)
#define DFIX 24   // packed fast-path depth, zero-padded; tail read from exact table
#define NF4 1066  // NN/4 float4s per row (17056 B, 16B-aligned)
#define NIT 17    // ceil(NF4/64) float4-iterations per wave

struct Keys { unsigned k0[NSTEP]; unsigned k1[NSTEP]; };

// ---- threefry2x32, exactly as JAX (20 rounds, key injections every 4) ----
#define TF_ROUND(x0, x1, r) { x0 += x1; x1 = (x1 << (r)) | (x1 >> (32 - (r))); x1 ^= x0; }
#define TF_BODY(K0, K1, C0, C1, O0, O1) {                                   \
  unsigned ks0 = (K0), ks1 = (K1), ks2 = (K0) ^ (K1) ^ 0x1BD11BDAu;          \
  unsigned x0 = (C0) + ks0, x1 = (C1) + ks1;                                 \
  TF_ROUND(x0, x1, 13) TF_ROUND(x0, x1, 15) TF_ROUND(x0, x1, 26) TF_ROUND(x0, x1, 6)  \
  x0 += ks1; x1 += ks2 + 1u;                                                 \
  TF_ROUND(x0, x1, 17) TF_ROUND(x0, x1, 29) TF_ROUND(x0, x1, 16) TF_ROUND(x0, x1, 24) \
  x0 += ks2; x1 += ks0 + 2u;                                                 \
  TF_ROUND(x0, x1, 13) TF_ROUND(x0, x1, 15) TF_ROUND(x0, x1, 26) TF_ROUND(x0, x1, 6)  \
  x0 += ks0; x1 += ks1 + 3u;                                                 \
  TF_ROUND(x0, x1, 17) TF_ROUND(x0, x1, 29) TF_ROUND(x0, x1, 16) TF_ROUND(x0, x1, 24) \
  x0 += ks1; x1 += ks2 + 4u;                                                 \
  TF_ROUND(x0, x1, 13) TF_ROUND(x0, x1, 15) TF_ROUND(x0, x1, 26) TF_ROUND(x0, x1, 6)  \
  x0 += ks2; x1 += ks0 + 5u;                                                 \
  (O0) = x0; (O1) = x1; }

static void tf_host(unsigned k0, unsigned k1, unsigned c0, unsigned c1,
                    unsigned* o0, unsigned* o1) {
  unsigned a, b;
  TF_BODY(k0, k1, c0, c1, a, b);
  *o0 = a; *o1 = b;
}

__device__ __forceinline__ void tf_dev(unsigned k0, unsigned k1, unsigned c0, unsigned c1,
                                       unsigned& o0, unsigned& o1) {
  TF_BODY(k0, k1, c0, c1, o0, o1);
}

// r(step, c) = u*2-1 from the xor-fold of threefry2x32(key_step, (0, c)) — the
// jax.random.uniform (threefry_partitionable) stream. Exact in f32.
__device__ __forceinline__ float tf_r(unsigned k0, unsigned k1, unsigned c) {
  unsigned o0, o1;
  tf_dev(k0, k1, 0u, c, o0, o1);
  const unsigned bits = o0 ^ o1;
  const float u = __uint_as_float((bits >> 9) | 0x3f800000u) - 1.0f;
  return u * 2.0f - 1.0f;
}

// ---- Build tables: wave-per-row, full-row register prefetch, no barriers ----
// Row p = g*GSZ + i -> node = groups[p].
// pack4[p*DFIX + k]  = (bf16_rne(val) << 16) | (col << 2)   (zero-padded;
//                      low half is the LDS *byte* offset of m[col])
// exact8[p*DMAX + k] = {col, f32 val}                       (ascending col)
// marg[p] = 2^-9 * sum_{k<DFIX} |val| + 2e-5                (screen margin bound)
__global__ __launch_bounds__(256) void build_ell(const float* __restrict__ J,
                                                 const int* __restrict__ groups,
                                                 unsigned* __restrict__ pack4,
                                                 int2* __restrict__ exact8,
                                                 int* __restrict__ deg,
                                                 float* __restrict__ marg) {
  const int wv = threadIdx.x >> 6, lane = threadIdx.x & 63;
  const int p = blockIdx.x * 4 + wv;
  if (p >= NN) return;
  const int node = groups[p];
  const float4* row = (const float4*)(J + (size_t)node * NN);

  // Phase 1: issue ALL row loads (17 KB/wave in flight -> BW-bound, not latency)
  float4 vv[NIT];
#pragma unroll
  for (int it = 0; it < NIT; ++it) {
    const int q = it * 64 + lane;
    vv[it] = (q < NF4) ? row[q] : make_float4(0.0f, 0.0f, 0.0f, 0.0f);
  }

  // Phase 2: ballot compaction on registers (exact ascending-column order)
  int cnt = 0;
  float asum = 0.0f;
#pragma unroll
  for (int it = 0; it < NIT; ++it) {
    const float4 v = vv[it];
    const int c0 = (it * 64 + lane) * 4;
#define COMP(X, CIDX) {                                                        \
      const bool nz = ((X) != 0.0f);                                           \
      const unsigned long long mk = __ballot(nz);                              \
      const int rk = cnt + __popcll(mk & ((1ull << lane) - 1ull));             \
      if (nz) {                                                                \
        if (rk < DFIX) {                                                       \
          const unsigned bits = __float_as_uint(X);                            \
          const unsigned bf = (bits + 0x7fffu + ((bits >> 16) & 1u)) >> 16;    \
          pack4[(size_t)p * DFIX + rk] = (bf << 16) | ((unsigned)(CIDX) << 2); \
          asum += fabsf(X);                                                    \
        }                                                                      \
        if (rk < DMAX)                                                         \
          exact8[(size_t)p * DMAX + rk] = make_int2((CIDX), __float_as_int(X));\
      }                                                                        \
      cnt += __popcll(mk); }
    COMP(v.x, c0 + 0) COMP(v.y, c0 + 1) COMP(v.z, c0 + 2) COMP(v.w, c0 + 3)
#undef COMP
  }
  for (int k = cnt + lane; k < DFIX; k += 64) pack4[(size_t)p * DFIX + k] = 0u;
  for (int s = 1; s < 64; s <<= 1) asum += __shfl_xor(asum, s, 64);
  if (lane == 0) {
    deg[p] = (cnt > DMAX) ? DMAX : cnt;
    marg[p] = asum * 0.001953125f + 2e-5f;  // 2^-9 * sum|v| + slack
  }
}

// ---- Full Gibbs chain: one workgroup per batch row (rows are independent) ----
// 576 threads = 9 waves, one node per thread per group-step.
// Two register pipelines, both one step ahead of consumption:
//  - pack words for group g+1 (constant table -> no barrier dependency)
//  - r for step s+1 (depends only on (step,b,i)) — the threefry 20-round
//    DEPENDENT chain (~400 cyc) retires inside the gather/barrier shadow
//    instead of stalling the compare at step top (r9's 540 cyc/step cost),
//    with none of the Atab prep/HBM cost (r8's 25 µs + 28 MB pollution).
__global__ __launch_bounds__(576, 3) void gibbs(const float* __restrict__ m0,
                                                const float* __restrict__ H,
                                                const int* __restrict__ groups,
                                                const unsigned* __restrict__ pack4,
                                                const int2* __restrict__ exact8,
                                                const int* __restrict__ deg,
                                                const float* __restrict__ marg,
                                                float* __restrict__ out,
                                                Keys keys) {
  __shared__ float m_lds[NN];
  const int b = blockIdx.x;
  const int i = threadIdx.x;
  const bool active = (i < GSZ);

  for (int n = i; n < NN; n += 576) m_lds[n] = m0[(size_t)b * NN + n];

  // Per-thread per-group preload (step-invariant).
  int nodeg[NGRP];
  float hg[NGRP], mgg[NGRP];
  int dgg[NGRP];
  if (active) {
#pragma unroll
    for (int g = 0; g < NGRP; ++g) {
      const int p = g * GSZ + i;
      nodeg[g] = groups[p];
      hg[g] = H[nodeg[g]];
      dgg[g] = deg[p];
      mgg[g] = marg[p];
    }
  }

  const unsigned c = (unsigned)(b * GSZ + i);

  // Prime both pipelines: group-0 pack words + step-0 random draw.
  uint4 w0, w1, w2, w3, w4, w5;
  float rcur = 0.0f;
  if (active) {
    const uint4* q = (const uint4*)(pack4 + (size_t)i * DFIX);
    w0 = q[0]; w1 = q[1]; w2 = q[2]; w3 = q[3]; w4 = q[4]; w5 = q[5];
    rcur = tf_r(keys.k0[0], keys.k1[0], c);
  }
  __syncthreads();

#pragma unroll 1
  for (int t = 0; t < NSWEEP; ++t) {
#pragma unroll
    for (int g = 0; g < NGRP; ++g) {
      const int step = t * NGRP + g;
      float nv = 0.0f;
      float rnext = 0.0f;
      uint4 n0, n1, n2, n3, n4, n5;
      if (active) {
        // Prefetch next group-step's pack words (independent of barriers).
        {
          const int gn = (g + 1) & (NGRP - 1);
          const uint4* qn = (const uint4*)(pack4 + (size_t)(gn * GSZ + i) * DFIX);
          n0 = qn[0]; n1 = qn[1]; n2 = qn[2]; n3 = qn[3]; n4 = qn[4]; n5 = qn[5];
        }
        // Start next step's threefry now: its dependent chain overlaps the
        // gather below and the barriers; consumed only next iteration.
        {
          const int sn = (step + 1 < NSTEP) ? step + 1 : step;
          rnext = tf_r(keys.k0[sn], keys.k1[sn], c);
        }

        // Gather-sum from current registers.
        float a0 = 0.0f, a1 = 0.0f, a2 = 0.0f, a3 = 0.0f;
        // value = high-16 bits as f32 (bf16<<16); addr = low-16 = byte offset
#define MV(W)  (*(const float*)((const char*)m_lds + ((W) & 0xFFFCu)))
#define ACC(W) \
        a0 += __uint_as_float((W).x & 0xFFFF0000u) * MV((W).x); \
        a1 += __uint_as_float((W).y & 0xFFFF0000u) * MV((W).y); \
        a2 += __uint_as_float((W).z & 0xFFFF0000u) * MV((W).z); \
        a3 += __uint_as_float((W).w & 0xFFFF0000u) * MV((W).w);
        ACC(w0) ACC(w1) ACC(w2) ACC(w3) ACC(w4) ACC(w5)
#undef ACC
#undef MV
        const int dg = dgg[g];
        const int2* ep = exact8 + (size_t)(g * GSZ + i) * DMAX;
        if (__builtin_expect(dg > DFIX, 0)) {
          for (int k = DFIX; k < dg; ++k) {
            const int2 e = ep[k];
            a0 += __int_as_float(e.y) * m_lds[e.x];
          }
        }
        const float I = ((a0 + a1) + (a2 + a3)) + hg[g];

        const float th = tanhf(I);
        const float d = th - rcur;
        if (__builtin_expect(fabsf(d) > mgg[g], 1)) {
          // |tanhf(I_fast) - tanh64(I_exact)| <= marg -> sign matches exact
          nv = (d > 0.0f) ? 1.0f : -1.0f;
        } else {
          // Boundary-close: settle in f64 from exact f32 table (ascending col).
          double I64 = (double)hg[g];
          for (int k = 0; k < dg; ++k) {
            const int2 e = ep[k];
            I64 += (double)__int_as_float(e.y) * (double)m_lds[e.x];
          }
          const double diff = tanh(I64) - (double)rcur;
          nv = (diff > 0.0) ? 1.0f : ((diff < 0.0) ? -1.0f : 0.0f);
        }
      }
      __syncthreads();                  // all gathers done
      if (active) m_lds[nodeg[g]] = nv; // compute-all-then-set semantics
      __syncthreads();                  // scatter visible before next group
      w0 = n0; w1 = n1; w2 = n2; w3 = n3; w4 = n4; w5 = n5;
      rcur = rnext;
    }
  }

  for (int n = i; n < NN; n += 576) out[(size_t)b * NN + n] = m_lds[n];
}

extern "C" void kernel_launch(void* const* d_in, const int* in_sizes, int n_in,
                              void* d_out, int out_size, void* d_ws, size_t ws_size,
                              hipStream_t stream) {
  const float* m0     = (const float*)d_in[0];
  const float* J      = (const float*)d_in[1];
  const float* H      = (const float*)d_in[2];
  const int*   groups = (const int*)d_in[3];
  // d_in[4] = sample_num (=10, hardcoded as NSWEEP)

  // Workspace: pack4[NN*DFIX] u32 (409 KB) | exact8[NN*DMAX] int2 (1.64 MB)
  //          | deg[NN] i32 | marg[NN] f32   -> ~2.08 MB total
  char* ws = (char*)d_ws;
  unsigned* pack4  = (unsigned*)ws;                     ws += (size_t)NN * DFIX * 4;
  int2*     exact8 = (int2*)ws;                         ws += (size_t)NN * DMAX * 8;
  int*      deg    = (int*)ws;                          ws += (size_t)NN * 4;
  float*    marg   = (float*)ws;

  // Host-side key schedule, jax_threefry_partitionable=True (fold-like split):
  // key(42) -> (0, 42); split(key, n)[i] = threefry2x32(key, (0, i)).
  Keys keys;
  for (int t = 0; t < NSWEEP; ++t) {
    unsigned ik0, ik1;
    tf_host(0u, 42u, 0u, (unsigned)t, &ik0, &ik1);
    for (int g = 0; g < NGRP; ++g) {
      unsigned gk0, gk1;
      tf_host(ik0, ik1, 0u, (unsigned)g, &gk0, &gk1);
      keys.k0[t * NGRP + g] = gk0;
      keys.k1[t * NGRP + g] = gk1;
    }
  }

  build_ell<<<(NN + 3) / 4, 256, 0, stream>>>(J, groups, pack4, exact8, deg, marg);
  gibbs<<<BB, 576, 0, stream>>>(m0, H, groups, pack4, exact8, deg, marg,
                                (float*)d_out, keys);
}